// Round 3
// baseline (1419.643 us; speedup 1.0000x reference)
//
#include <hip/hip_runtime.h>

#define B_ 512
#define T_ 512

typedef __bf16 bf16x8 __attribute__((ext_vector_type(8)));
typedef float  f32x4  __attribute__((ext_vector_type(4)));
using u16 = unsigned short;

__device__ __forceinline__ float fast_rcp(float x) { return __builtin_amdgcn_rcpf(x); }
__device__ __forceinline__ float sigf(float x)     { return fast_rcp(1.0f + __expf(-x)); }
__device__ __forceinline__ float tanhfast(float x) { return 1.0f - 2.0f * fast_rcp(__expf(2.0f * x) + 1.0f); }

// fp32 -> bf16 RNE
__device__ __forceinline__ u16 f2bf(float f) {
    unsigned u = __float_as_uint(f);
    u += 0x7FFFu + ((u >> 16) & 1u);
    return (u16)(u >> 16);
}

// Light barrier: orders LDS only; global stores stay in flight across ticks.
__device__ __forceinline__ void lbar() {
    asm volatile("s_waitcnt lgkmcnt(0)\n\ts_barrier" ::: "memory");
}

// DPP quad-perm move. 0xB1 = quad_perm[1,0,3,2], 0x4E = quad_perm[2,3,0,1].
template<int CTRL>
__device__ __forceinline__ float dppq(float v) {
    int r = __builtin_amdgcn_update_dpp(0, __float_as_int(v), CTRL, 0xF, 0xF, true);
    return __int_as_float(r);
}

// Staging stride for L3 f32 output tile: 132 = 128+4 -> 2-way banks (free),
// 16B-aligned rows for dwordx4 flush.
constexpr int OSTR = 132;

// One LSTM layer's per-wave state + step. All loops compile-time unrolled so
// WB/bias/cst stay in registers (rule #20). DSS = downstream LDS row stride
// (u16 units); GOUT = last layer stages f32 h into LDS (coalesced flush later).
template<int D, int H, int TPW, int DSS, bool GOUT>
struct LL {
    static constexpr int K    = D + H;
    static constexpr int KF   = (K + 31) / 32;
    static constexpr int SSTR = KF * 32 + 8;   // u16: 16B-aligned rows, bank-spread

    bf16x8 WB[TPW][KF];
    float  bias[TPW][4];
    float  cst[TPW];
    int    tile[TPW];   // wave-uniform
    bool   tv[TPW];     // tile valid (wave-uniform)

    __device__ __forceinline__ void init(const float* __restrict__ Wih,
                                         const float* __restrict__ Whh,
                                         const float* __restrict__ bih,
                                         const float* __restrict__ bhh,
                                         int lane) {
        const int q = lane >> 4, cc = lane & 15;
#pragma unroll
        for (int tp = 0; tp < TPW; ++tp) {
            cst[tp] = 0.0f;
            if (tv[tp]) {
                const int nglob = tile[tp] * 16 + cc;     // gate-interleaved col n=4u+g
                const int u = nglob >> 2, g = nglob & 3;
                const int row = g * H + u;
#pragma unroll
                for (int kf = 0; kf < KF; ++kf) {
                    bf16x8 w;
#pragma unroll
                    for (int jj = 0; jj < 8; ++jj) {
                        const int k = kf * 32 + q * 8 + jj;
                        float v = 0.0f;
                        if (k < D)      v = Wih[row * D + k];
                        else if (k < K) v = Whh[row * H + (k - D)];
                        w[jj] = (__bf16)v;
                    }
                    WB[tp][kf] = w;
                }
                const int uu = tile[tp] * 4 + (cc >> 2);
#pragma unroll
                for (int g2 = 0; g2 < 4; ++g2)
                    bias[tp][g2] = bih[g2 * H + uu] + bhh[g2 * H + uu];
            } else {
#pragma unroll
                for (int kf = 0; kf < KF; ++kf)
#pragma unroll
                    for (int jj = 0; jj < 8; ++jj) WB[tp][kf][jj] = (__bf16)0.0f;
#pragma unroll
                for (int g2 = 0; g2 < 4; ++g2) bias[tp][g2] = 0.0f;
            }
        }
    }

    // cur: input buffer (x | h_{t-1}); own: buffer receiving h_t (cols D..D+H);
    // down: next layer's buffer receiving h_t as x (cols 0..H).
    // GOUT: stg = LDS f32 staging tile [16][OSTR] for this tick's parity.
    __device__ __forceinline__ void step(const u16* __restrict__ cur,
                                         u16* __restrict__ own,
                                         u16* __restrict__ down,
                                         float* __restrict__ stg,
                                         int lane) {
        const int q = lane >> 4, cc = lane & 15;
        bf16x8 A[KF];
#pragma unroll
        for (int kf = 0; kf < KF; ++kf)
            A[kf] = *(const bf16x8*)&cur[cc * SSTR + kf * 32 + q * 8];

        f32x4 acc[TPW];
#pragma unroll
        for (int tp = 0; tp < TPW; ++tp) acc[tp] = f32x4{0.f, 0.f, 0.f, 0.f};
#pragma unroll
        for (int kf = 0; kf < KF; ++kf)
#pragma unroll
            for (int tp = 0; tp < TPW; ++tp)
                acc[tp] = __builtin_amdgcn_mfma_f32_16x16x32_bf16(A[kf], WB[tp][kf], acc[tp], 0, 0, 0);

        const bool bA = lane & 1, bB = lane & 2;
        const int  rr = 4 * q + (lane & 3);               // batch row after transpose
#pragma unroll
        for (int tp = 0; tp < TPW; ++tp) {
            if (tv[tp]) {
                float v0 = acc[tp][0], v1 = acc[tp][1], v2 = acc[tp][2], v3 = acc[tp][3];
                float s;
                s = dppq<0xB1>(bA ? v0 : v1); if (bA) v0 = s; else v1 = s;
                s = dppq<0xB1>(bA ? v2 : v3); if (bA) v2 = s; else v3 = s;
                s = dppq<0x4E>(bB ? v0 : v2); if (bB) v0 = s; else v2 = s;
                s = dppq<0x4E>(bB ? v1 : v3); if (bB) v1 = s; else v3 = s;

                const float gi = sigf(v0 + bias[tp][0]);
                const float gf = sigf(v1 + bias[tp][1]);
                const float gg = tanhfast(v2 + bias[tp][2]);
                const float go = sigf(v3 + bias[tp][3]);
                const float c  = gf * cst[tp] + gi * gg;
                cst[tp] = c;
                const float h  = go * tanhfast(c);

                const int u = tile[tp] * 4 + (cc >> 2);
                own[rr * SSTR + D + u] = f2bf(h);         // own-h feedback
                if constexpr (GOUT) {
                    stg[rr * OSTR + u] = h;               // f32 staging, 2-way banks
                } else {
                    down[rr * DSS + u] = f2bf(h);         // next layer's x
                }
            }
        }
    }
};

// Fused 3-layer pipelined LSTM. One block = 16 batch rows through all layers.
// Tick tau: L1 step tau, L2 step tau-1, L3 step tau-2. Parity rule: layer at
// step s reads buf[s&1], writes own-h to buf[(s+1)&1], downstream-h to
// buf_next[s&1] — one lbar per tick.
// L3 output is staged in LDS (f32) and flushed COALESCED at the top of the
// next tick: replaces 2048 scattered store transactions/block/tick with 8
// dwordx4 bursts, and leaves the end-of-tick vmcnt(0) (before the x ds_write)
// with nothing left to drain.
constexpr int S1 = 104, S2 = 104, S3 = 200;
constexpr int B1W = 16 * S1, B2W = 16 * S2, B3W = 16 * S3;
constexpr int SMW = 2 * (B1W + B2W + B3W);   // 13056 u16 = 26112 B

__global__ __launch_bounds__(512)
void lstm3_fused(const float* __restrict__ z,
                 const float* __restrict__ Wih1, const float* __restrict__ Whh1,
                 const float* __restrict__ bih1, const float* __restrict__ bhh1,
                 const float* __restrict__ Wih2, const float* __restrict__ Whh2,
                 const float* __restrict__ bih2, const float* __restrict__ bhh2,
                 const float* __restrict__ Wih3, const float* __restrict__ Whh3,
                 const float* __restrict__ bih3, const float* __restrict__ bhh3,
                 float* __restrict__ out, float* __restrict__ hn)
{
    __shared__ u16 smem[SMW];
    __shared__ float stg[2][16][OSTR];        // 16896 B; total LDS 43008 B
    u16* b1 = smem;
    u16* b2 = smem + 2 * B1W;
    u16* b3 = b2 + 2 * B2W;

    const int tid  = threadIdx.x;
    const int lane = tid & 63;
    const int wvu  = __builtin_amdgcn_readfirstlane(tid >> 6);  // SGPR wave id
    const int b0   = blockIdx.x * 16;

    static_assert(LL<64, 32, 1, S2, false>::SSTR == S1, "S1");
    static_assert(LL<32, 48, 2, S3, false>::SSTR == S2, "S2");
    static_assert(LL<48, 128, 4, 0, true>::SSTR == S3, "S3");

    LL<64, 32, 1, S2, false> l1;   // D=64  H=32  : 8 tiles  -> 1/wave
    LL<32, 48, 2, S3, false> l2;   // D=32  H=48  : 12 tiles -> 2/wave (tile1 on wv<4)
    LL<48, 128, 4, 0, true>  l3;   // D=48  H=128 : 32 tiles -> 4/wave

    l1.tile[0] = wvu;      l1.tv[0] = true;
    l2.tile[0] = wvu;      l2.tv[0] = true;
    l2.tile[1] = 8 + wvu;  l2.tv[1] = (wvu < 4);
#pragma unroll
    for (int tp = 0; tp < 4; ++tp) { l3.tile[tp] = wvu + 8 * tp; l3.tv[tp] = true; }

    l1.init(Wih1, Whh1, bih1, bhh1, lane);
    l2.init(Wih2, Whh2, bih2, bhh2, lane);
    l3.init(Wih3, Whh3, bih3, bhh3, lane);

    // zero x/h buffers (incl. K..KF*32 padding — must stay 0), then stage x_0
    for (int i = tid; i < SMW; i += 512) smem[i] = 0;
    lbar();

    const int xr = tid >> 5, xp = tid & 31;          // 512 thr = 16 rows x 32 dwords
    int xoff = (b0 + xr) * (T_ * 32) + xp;           // float2 index; fits int
    {
        const float2 f = ((const float2*)z)[xoff];
        const unsigned pk = (unsigned)f2bf(f.x) | ((unsigned)f2bf(f.y) << 16);
        *(unsigned*)&b1[xr * S1 + 2 * xp] = pk;      // parity 0 = step-0 cur
    }
    xoff += 32;
    lbar();

    const int fr  = tid >> 5;                        // flush row 0..15
    const int fc4 = (tid & 31) << 2;                 // flush col 0..124 step 4

    for (int tick = 0; tick < T_ + 2; ++tick) {
        const int qq = tick & 1;
        u16* b1c = b1 + qq * B1W;        u16* b1n = b1 + (qq ^ 1) * B1W;
        u16* b2c = b2 + (qq ^ 1) * B2W;  u16* b2n = b2 + qq * B2W;
        u16* b3c = b3 + qq * B3W;        u16* b3n = b3 + (qq ^ 1) * B3W;

        // ---- coalesced flush of L3 output t = tick-3 (staged last tick) ----
        // Issued FIRST so the stores retire during this tick's compute.
        if (tick >= 3) {
            const f32x4 v = *(const f32x4*)&stg[qq ^ 1][fr][fc4];
            *(f32x4*)&out[((size_t)(b0 + fr) * T_ + (tick - 3)) * 128 + fc4] = v;
        }

        // prefetch x_{tick+1} early; ds_write at tick end
        unsigned pk = 0;
        const bool hasx = (tick + 1 < T_);
        if (hasx) {
            const float2 f = ((const float2*)z)[xoff];
            pk = (unsigned)f2bf(f.x) | ((unsigned)f2bf(f.y) << 16);
        }
        xoff += 32;

        if (tick < T_)
            l1.step(b1c, b1n, b2n, nullptr, lane);
        if (tick >= 1 && tick <= T_)
            l2.step(b2c, b2n, b3n, nullptr, lane);
        if (tick >= 2)
            l3.step(b3c, b3n, nullptr, &stg[qq][0][0], lane);

        if (hasx) *(unsigned*)&b1n[xr * S1 + 2 * xp] = pk;
        lbar();
    }

    // ---- epilogue: flush t = T_-1 (staged at parity (T_+1)&1) + h_n (f32) ----
    {
        const f32x4 v = *(const f32x4*)&stg[(T_ + 1) & 1][fr][fc4];
        *(f32x4*)&out[((size_t)(b0 + fr) * T_ + (T_ - 1)) * 128 + fc4] = v;
        *(f32x4*)&hn[(size_t)(b0 + fr) * 128 + fc4] = v;
    }
}

extern "C" void kernel_launch(void* const* d_in, const int* in_sizes, int n_in,
                              void* d_out, int out_size, void* d_ws, size_t ws_size,
                              hipStream_t stream)
{
    (void)in_sizes; (void)n_in; (void)out_size; (void)d_ws; (void)ws_size;
    const float* z    = (const float*)d_in[0];
    const float* Wih1 = (const float*)d_in[1];
    const float* Whh1 = (const float*)d_in[2];
    const float* bih1 = (const float*)d_in[3];
    const float* bhh1 = (const float*)d_in[4];
    const float* Wih2 = (const float*)d_in[5];
    const float* Whh2 = (const float*)d_in[6];
    const float* bih2 = (const float*)d_in[7];
    const float* bhh2 = (const float*)d_in[8];
    const float* Wih3 = (const float*)d_in[9];
    const float* Whh3 = (const float*)d_in[10];
    const float* bih3 = (const float*)d_in[11];
    const float* bhh3 = (const float*)d_in[12];

    float* out = (float*)d_out;                   // [B,T,128]
    float* hn  = out + (size_t)B_ * T_ * 128;     // [1,B,128]

    hipLaunchKernelGGL(lstm3_fused, dim3(32), dim3(512), 0, stream,
                       z, Wih1, Whh1, bih1, bhh1,
                       Wih2, Whh2, bih2, bhh2,
                       Wih3, Whh3, bih3, bhh3, out, hn);
}

// Round 6
// 961.468 us; speedup vs baseline: 1.4765x; 1.4765x over previous
//
#include <hip/hip_runtime.h>

#define B_ 512
#define T_ 512

typedef __bf16 bf16x8 __attribute__((ext_vector_type(8)));
typedef float  f32x4  __attribute__((ext_vector_type(4)));
using u16 = unsigned short;

__device__ __forceinline__ float fast_rcp(float x) { return __builtin_amdgcn_rcpf(x); }
__device__ __forceinline__ float sigf(float x)     { return fast_rcp(1.0f + __expf(-x)); }
__device__ __forceinline__ float tanhfast(float x) { return 1.0f - 2.0f * fast_rcp(__expf(2.0f * x) + 1.0f); }

// fp32 -> bf16 RNE
__device__ __forceinline__ u16 f2bf(float f) {
    unsigned u = __float_as_uint(f);
    u += 0x7FFFu + ((u >> 16) & 1u);
    return (u16)(u >> 16);
}

// Light barrier: orders LDS only; global stores stay in flight across ticks.
__device__ __forceinline__ void lbar() {
    asm volatile("s_waitcnt lgkmcnt(0)\n\ts_barrier" ::: "memory");
}

// DPP row_shr:8 (ctrl 0x118): dst lane i <- src lane i-8 within each 16-lane
// row (data moves toward HIGHER lanes; canonical DPP prefix-sum direction);
// dst lanes (i%16)<8 get 0 (bound_ctrl). Merges tile-B's batch rows (lanes
// cc 0-7) into lanes cc 8-15 of the packed gate computation.
__device__ __forceinline__ float dpp_shr8(float v) {
    int r = __builtin_amdgcn_update_dpp(0, __float_as_int(v), 0x118, 0xF, 0xF, true);
    return __int_as_float(r);
}

// Staging stride for L3 f32 output tile (8 rows x 128 units): 132 -> spread
// banks, 16B-aligned rows for dwordx4 flush.
constexpr int OSTR = 132;

// One LSTM layer, swapped-operand MFMA form: acc = mfma(W_frag, x_frag) gives
// D[gatecol, batch] => lane (q=lane>>4, cc=lane&15) holds gates i,f,g,o in
// regs 0..3 for unit tile*4+q, batch row cc. NO transpose needed (A- and
// B-fragment lane layouts are identical, so the same register contents serve
// either operand slot).
// 8-row blocks: real batch rows are cc 0..7 (LDS rows 8..15 stay zero).
// Pair-packing: each pack owns tiles (tA,tB); after MFMA, tB's rows (lanes
// cc<8) are moved to lanes cc>=8 via dpp row_shr:8 + cndmask, so all 64 lanes
// compute gates for a real (row, unit): row = cc&7, unit = (cc<8?tA:tB)*4+q.
// NPK packs per wave; act = wave-uniform participation flag.
template<int D, int H, int NPK, int DSS, bool GOUT>
struct LL {
    static constexpr int K    = D + H;
    static constexpr int KF   = (K + 31) / 32;
    static constexpr int SSTR = KF * 32 + 8;   // u16: 16B-aligned rows, bank-spread

    bf16x8 WB[NPK][2][KF];   // weight fragments, both tiles of each pack
    float  biasP[NPK][4];    // per-lane effective bias (gate 0..3)
    float  cst[NPK];         // per-lane c-state for (row cc&7, unit uEff)
    int    ownOff[NPK];      // LDS u16 offset for own-h write
    int    dnOff[NPK];       // LDS offset for downstream write (u16) or stg (f32)
    bool   act;              // wave-uniform

    __device__ __forceinline__ void init(const float* __restrict__ Wih,
                                         const float* __restrict__ Whh,
                                         const float* __restrict__ bih,
                                         const float* __restrict__ bhh,
                                         int lane, int pairBase, bool active) {
        act = active;
        const int q = lane >> 4, cc = lane & 15;
#pragma unroll
        for (int p = 0; p < NPK; ++p) {
            cst[p] = 0.0f;
            const int tA = pairBase + 2 * p, tB = tA + 1;
#pragma unroll
            for (int s = 0; s < 2; ++s) {
                const int nglob = (s ? tB : tA) * 16 + cc;   // gatecol, n=4u+g order
                const int u = nglob >> 2, g = nglob & 3;
                const int row = g * H + u;
#pragma unroll
                for (int kf = 0; kf < KF; ++kf) {
                    bf16x8 w;
#pragma unroll
                    for (int jj = 0; jj < 8; ++jj) {
                        const int k = kf * 32 + q * 8 + jj;
                        float v = 0.0f;
                        if (active) {
                            if (k < D)      v = Wih[row * D + k];
                            else if (k < K) v = Whh[row * H + (k - D)];
                        }
                        w[jj] = (__bf16)v;
                    }
                    WB[p][s][kf] = w;
                }
            }
            const int tE = (cc < 8) ? tA : tB;
            const int uE = tE * 4 + q;
#pragma unroll
            for (int g2 = 0; g2 < 4; ++g2)
                biasP[p][g2] = active ? (bih[g2 * H + uE] + bhh[g2 * H + uE]) : 0.0f;
            ownOff[p] = (cc & 7) * SSTR + D + uE;
            dnOff[p]  = (cc & 7) * (GOUT ? OSTR : DSS) + uE;
        }
    }

    // cur: input buffer (x | h_{t-1}); own: buffer receiving h_t (cols D..D+H);
    // down: next layer's x region; stgf: L3 f32 staging tile.
    __device__ __forceinline__ void step(const u16* __restrict__ cur,
                                         u16* __restrict__ own,
                                         u16* __restrict__ down,
                                         float* __restrict__ stgf,
                                         int lane) {
        if (!act) return;
        const int q = lane >> 4, cc = lane & 15;
        bf16x8 A[KF];
#pragma unroll
        for (int kf = 0; kf < KF; ++kf)
            A[kf] = *(const bf16x8*)&cur[cc * SSTR + kf * 32 + q * 8];

        const bool hi = (cc >= 8);
#pragma unroll
        for (int p = 0; p < NPK; ++p) {
            f32x4 a0 = {0.f, 0.f, 0.f, 0.f}, a1 = {0.f, 0.f, 0.f, 0.f};
#pragma unroll
            for (int kf = 0; kf < KF; ++kf) {
                a0 = __builtin_amdgcn_mfma_f32_16x16x32_bf16(WB[p][0][kf], A[kf], a0, 0, 0, 0);
                a1 = __builtin_amdgcn_mfma_f32_16x16x32_bf16(WB[p][1][kf], A[kf], a1, 0, 0, 0);
            }
            // merge tile B rows into lanes cc>=8 (DPP executes for all lanes)
            const float s0 = dpp_shr8(a1[0]);
            const float s1 = dpp_shr8(a1[1]);
            const float s2 = dpp_shr8(a1[2]);
            const float s3 = dpp_shr8(a1[3]);
            const float v0 = hi ? s0 : a0[0];
            const float v1 = hi ? s1 : a0[1];
            const float v2 = hi ? s2 : a0[2];
            const float v3 = hi ? s3 : a0[3];

            const float gi = sigf(v0 + biasP[p][0]);
            const float gf = sigf(v1 + biasP[p][1]);
            const float gg = tanhfast(v2 + biasP[p][2]);
            const float go = sigf(v3 + biasP[p][3]);
            const float c  = gf * cst[p] + gi * gg;
            cst[p] = c;
            const float h  = go * tanhfast(c);
            const u16 hb = f2bf(h);

            own[ownOff[p]] = hb;                       // own-h feedback (rows 0..7)
            if constexpr (GOUT) stgf[dnOff[p]] = h;    // f32 staging
            else                down[dnOff[p]] = hb;   // next layer's x
        }
    }
};

// Fused 3-layer pipelined LSTM, 64 blocks x 8 batch rows (2x the CUs of the
// 16-row version; gate VALU per wave ~halved via pair-packing).
// Tick tau: L1 step tau, L2 step tau-1, L3 step tau-2. Parity rule unchanged
// (field-verified): layer at step s reads buf[s&1], writes own-h to
// buf[(s+1)&1], downstream to buf_next[s&1]; one lbar per tick.
constexpr int S1 = 104, S2 = 104, S3 = 200;
constexpr int B1W = 16 * S1, B2W = 16 * S2, B3W = 16 * S3;
constexpr int SMW = 2 * (B1W + B2W + B3W);   // 26112 B

__global__ __launch_bounds__(512, 2)   // 2 waves/EU -> 1 block/CU -> 256 VGPR/wave
void lstm3_fused(const float* __restrict__ z,
                 const float* __restrict__ Wih1, const float* __restrict__ Whh1,
                 const float* __restrict__ bih1, const float* __restrict__ bhh1,
                 const float* __restrict__ Wih2, const float* __restrict__ Whh2,
                 const float* __restrict__ bih2, const float* __restrict__ bhh2,
                 const float* __restrict__ Wih3, const float* __restrict__ Whh3,
                 const float* __restrict__ bih3, const float* __restrict__ bhh3,
                 float* __restrict__ out, float* __restrict__ hn)
{
    __shared__ u16 smem[SMW];
    __shared__ float stg[2][8][OSTR];          // 8448 B; total LDS ~34.5 KB
    u16* b1 = smem;
    u16* b2 = smem + 2 * B1W;
    u16* b3 = b2 + 2 * B2W;

    const int tid  = threadIdx.x;
    const int lane = tid & 63;
    const int wvu  = __builtin_amdgcn_readfirstlane(tid >> 6);
    const int b0   = blockIdx.x * 8;

    static_assert(LL<64, 32, 1, S2, false>::SSTR == S1, "S1");
    static_assert(LL<32, 48, 1, S3, false>::SSTR == S2, "S2");
    static_assert(LL<48, 128, 2, 0, true>::SSTR == S3, "S3");

    LL<64, 32, 1, S2, false> l1;   // H=32:  8 tiles = 4 pairs  -> waves 0-3
    LL<32, 48, 1, S3, false> l2;   // H=48: 12 tiles = 6 pairs  -> waves 2-7
    LL<48, 128, 2, 0, true>  l3;   // H=128:32 tiles = 16 pairs -> 2 pairs/wave

    l1.init(Wih1, Whh1, bih1, bhh1, lane, 2 * wvu, wvu < 4);
    l2.init(Wih2, Whh2, bih2, bhh2, lane, (wvu >= 2) ? 2 * (wvu - 2) : 0, wvu >= 2);
    l3.init(Wih3, Whh3, bih3, bhh3, lane, 4 * wvu, true);

    // zero x/h buffers (rows 8-15 and K..KF*32 padding must stay 0)
    for (int i = tid; i < SMW; i += 512) smem[i] = 0;
    lbar();

    // x staging: 8 rows x 32 float2 -> threads 0..255
    const int xr = tid >> 5, xp = tid & 31;
    const bool stgx = (tid < 256);
    int xoff = (b0 + xr) * (T_ * 32) + xp;
    if (stgx) {
        const float2 f = ((const float2*)z)[xoff];
        const unsigned pk = (unsigned)f2bf(f.x) | ((unsigned)f2bf(f.y) << 16);
        *(unsigned*)&b1[xr * S1 + 2 * xp] = pk;      // parity 0 = step-0 cur
    }
    xoff += 32;
    lbar();

    const int fr  = tid >> 5;                        // flush row 0..7 (tid<256)
    const int fc4 = (tid & 31) << 2;                 // flush col 0..124 step 4

    for (int tick = 0; tick < T_ + 2; ++tick) {
        const int qq = tick & 1;
        u16* b1c = b1 + qq * B1W;        u16* b1n = b1 + (qq ^ 1) * B1W;
        u16* b2c = b2 + (qq ^ 1) * B2W;  u16* b2n = b2 + qq * B2W;
        u16* b3c = b3 + qq * B3W;        u16* b3n = b3 + (qq ^ 1) * B3W;

        // coalesced flush of L3 output t = tick-3 (staged last tick)
        if (tick >= 3 && stgx) {
            const f32x4 v = *(const f32x4*)&stg[qq ^ 1][fr][fc4];
            *(f32x4*)&out[((size_t)(b0 + fr) * T_ + (tick - 3)) * 128 + fc4] = v;
        }

        // prefetch x_{tick+1}; ds_write at tick end
        unsigned pk = 0;
        const bool hasx = stgx && (tick + 1 < T_);
        if (hasx) {
            const float2 f = ((const float2*)z)[xoff];
            pk = (unsigned)f2bf(f.x) | ((unsigned)f2bf(f.y) << 16);
        }
        xoff += 32;

        if (tick < T_)
            l1.step(b1c, b1n, b2n, nullptr, lane);
        if (tick >= 1 && tick <= T_)
            l2.step(b2c, b2n, b3n, nullptr, lane);
        if (tick >= 2)
            l3.step(b3c, b3n, nullptr, &stg[qq][0][0], lane);

        if (hasx) *(unsigned*)&b1n[xr * S1 + 2 * xp] = pk;
        lbar();
    }

    // epilogue: flush t = T_-1 (parity (T_+1)&1) + h_n (f32)
    if (stgx) {
        const f32x4 v = *(const f32x4*)&stg[(T_ + 1) & 1][fr][fc4];
        *(f32x4*)&out[((size_t)(b0 + fr) * T_ + (T_ - 1)) * 128 + fc4] = v;
        *(f32x4*)&hn[(size_t)(b0 + fr) * 128 + fc4] = v;
    }
}

extern "C" void kernel_launch(void* const* d_in, const int* in_sizes, int n_in,
                              void* d_out, int out_size, void* d_ws, size_t ws_size,
                              hipStream_t stream)
{
    (void)in_sizes; (void)n_in; (void)out_size; (void)d_ws; (void)ws_size;
    const float* z    = (const float*)d_in[0];
    const float* Wih1 = (const float*)d_in[1];
    const float* Whh1 = (const float*)d_in[2];
    const float* bih1 = (const float*)d_in[3];
    const float* bhh1 = (const float*)d_in[4];
    const float* Wih2 = (const float*)d_in[5];
    const float* Whh2 = (const float*)d_in[6];
    const float* bih2 = (const float*)d_in[7];
    const float* bhh2 = (const float*)d_in[8];
    const float* Wih3 = (const float*)d_in[9];
    const float* Whh3 = (const float*)d_in[10];
    const float* bih3 = (const float*)d_in[11];
    const float* bhh3 = (const float*)d_in[12];

    float* out = (float*)d_out;                   // [B,T,128]
    float* hn  = out + (size_t)B_ * T_ * 128;     // [1,B,128]

    hipLaunchKernelGGL(lstm3_fused, dim3(64), dim3(512), 0, stream,
                       z, Wih1, Whh1, bih1, bhh1,
                       Wih2, Whh2, bih2, bhh2,
                       Wih3, Whh3, bih3, bhh3, out, hn);
}